// Round 4
// baseline (187.239 us; speedup 1.0000x reference)
//
#include <hip/hip_runtime.h>
#include <hip/hip_bf16.h>

// CausalSelfAttention  B=1, T=4096, C=768, H=12, hd=64
// Round 18: R17 post-mortem: flash is LDS-read-bandwidth bound (each wave
//   reads the full K,V tile per iter: 64KB LDS reads per 16KB staged, ~31us
//   of LDS pipe per CU). Fix: 32 q-rows per wave (QBLK=128) -> each K/V
//   frag read feeds 2 MFMAs (LDS bytes/MFMA halved), block-iters halve
//   (12672 vs 24960), per-iter VALU overhead halved. Restore R16-proven
//   triple-buffer + counted vmcnt(4). 756 equal-ish blocks (3/CU, one
//   scheduling round), depth<=22, 3 partial slots (ws layout = R17 size).

#define T_SEQ 4096
#define C_DIM 768
#define C3    2304
#define NH    12
#define HD    64

typedef __attribute__((ext_vector_type(8))) short bf16x8;
typedef __attribute__((ext_vector_type(4))) short bf16x4;
typedef __attribute__((ext_vector_type(4))) float f32x4;

__device__ inline unsigned short f2bf(float f) {
  union { float f; unsigned u; } v; v.f = f;
  unsigned r = v.u + 0x7fff + ((v.u >> 16) & 1);  // RTNE
  return (unsigned short)(r >> 16);
}
__device__ inline unsigned short f2bf_trunc(float f) {
  union { float f; unsigned u; } v; v.f = f;
  return (unsigned short)(v.u >> 16);  // truncate: fine for P >= 0
}

__device__ inline void gl2lds16(const void* g, void* l) {
  __builtin_amdgcn_global_load_lds(
      (const __attribute__((address_space(1))) unsigned int*)g,
      (__attribute__((address_space(3))) unsigned int*)l, 16, 0, 0);
}

#if __has_builtin(__builtin_amdgcn_exp2f)
#define EXP2F(x) __builtin_amdgcn_exp2f(x)
#else
#define EXP2F(x) exp2f(x)
#endif

// ---------------------------------------------------------------------------
// fused prep: conv x->bf16 | transpose w_qkv | transpose w_proj
// ---------------------------------------------------------------------------
#define NB_CONV  (T_SEQ * C_DIM / 2048)          // 1536
#define NB_TQKV  ((C3 / 32) * (C_DIM / 32))      // 1728
#define NB_TPROJ ((C_DIM / 32) * (C_DIM / 32))   // 576

__global__ __launch_bounds__(256) void prep_fused(
    const float* __restrict__ x, const float* __restrict__ w_qkv,
    const float* __restrict__ w_proj, unsigned short* __restrict__ xb,
    unsigned short* __restrict__ wqkvT, unsigned short* __restrict__ wprojT) {
  __shared__ float t[32][33];
  const int b = blockIdx.x;
  const int tid = threadIdx.x;

  if (b < NB_CONV) {
    int i = (b * 256 + tid) * 8;
    float4 v0 = *(const float4*)(x + i);
    float4 v1 = *(const float4*)(x + i + 4);
    unsigned short o[8] = {f2bf(v0.x), f2bf(v0.y), f2bf(v0.z), f2bf(v0.w),
                           f2bf(v1.x), f2bf(v1.y), f2bf(v1.z), f2bf(v1.w)};
    *(uint4*)(xb + i) = *(uint4*)o;
    return;
  }
  const float* in;
  unsigned short* outT;
  int R, Cc, bi;
  if (b < NB_CONV + NB_TQKV) {
    in = w_qkv; outT = wqkvT; R = C_DIM; Cc = C3; bi = b - NB_CONV;
  } else {
    in = w_proj; outT = wprojT; R = C_DIM; Cc = C_DIM; bi = b - NB_CONV - NB_TQKV;
  }
  const int tx = tid & 31, ty = tid >> 5;
  const int c0 = (bi % (Cc / 32)) * 32, r0 = (bi / (Cc / 32)) * 32;
#pragma unroll
  for (int i = 0; i < 4; ++i) {
    int r = ty + i * 8;
    t[r][tx] = in[(size_t)(r0 + r) * Cc + c0 + tx];
  }
  __syncthreads();
#pragma unroll
  for (int i = 0; i < 4; ++i) {
    int c = ty + i * 8;
    outT[(size_t)(c0 + c) * R + r0 + tx] = f2bf(t[tx][c]);
  }
}

// ---------------------------------------------------------------------------
// gemm1: qkv = xb @ wqkvT^T + b_qkv; V blocks write k-permuted vTp directly.
// Q columns (n < 768) pre-scaled by 0.125*log2(e).
// ---------------------------------------------------------------------------
__global__ __launch_bounds__(256) void gemm_qkv(
    const unsigned short* __restrict__ A, const unsigned short* __restrict__ Bt,
    const float* __restrict__ bias, unsigned short* __restrict__ Cq,
    unsigned short* __restrict__ vTp, int M, int N, int K) {
  __shared__ unsigned short As[128 * 64];
  __shared__ unsigned short Bs[128 * 64];
  const int tid = threadIdx.x;
  const int wave = tid >> 6, lane = tid & 63;
  const int lo = lane & 15, g8 = lane >> 4;
  const int lo7 = lo & 7;
  const int wm = wave >> 1, wn = wave & 1;
  const int bm = blockIdx.y * 128, bn = blockIdx.x * 128;
  const int drow8 = lane >> 3;               // 0..7
  const int dslot = (lane & 7) * 8;
  const int dsrc = ((lane & 7) ^ drow8) * 8; // swizzled source chunk

  f32x4 acc[4][4];
#pragma unroll
  for (int mt = 0; mt < 4; ++mt)
#pragma unroll
    for (int nt = 0; nt < 4; ++nt) acc[mt][nt] = (f32x4){0.f, 0.f, 0.f, 0.f};

  const unsigned short* Abase = A + (size_t)bm * K;
  const unsigned short* Bbase = Bt + (size_t)bn * K;

  for (int k0 = 0; k0 < K; k0 += 64) {
    __syncthreads();
#pragma unroll
    for (int p = 0; p < 4; ++p) {
      const int r = p * 32 + wave * 8 + drow8;
      gl2lds16(Abase + (size_t)r * K + k0 + dsrc, As + r * 64 + dslot);
      gl2lds16(Bbase + (size_t)r * K + k0 + dsrc, Bs + r * 64 + dslot);
    }
    __syncthreads();

#pragma unroll
    for (int kk = 0; kk < 2; ++kk) {
      bf16x8 a[4], b[4];
#pragma unroll
      for (int mt = 0; mt < 4; ++mt)
        a[mt] = *(const bf16x8*)(
            As + (wm * 64 + mt * 16 + lo) * 64 + (((kk * 4 + g8) ^ lo7) * 8));
#pragma unroll
      for (int nt = 0; nt < 4; ++nt)
        b[nt] = *(const bf16x8*)(
            Bs + (wn * 64 + nt * 16 + lo) * 64 + (((kk * 4 + g8) ^ lo7) * 8));
#pragma unroll
      for (int mt = 0; mt < 4; ++mt)
#pragma unroll
        for (int nt = 0; nt < 4; ++nt)
          acc[mt][nt] = __builtin_amdgcn_mfma_f32_16x16x32_bf16(a[mt], b[nt], acc[mt][nt], 0, 0, 0);
    }
  }

  if (bn < 2 * C_DIM) {
    const float sc = (bn < C_DIM) ? 0.18033688011112042f : 1.0f;  // 0.125*log2e
#pragma unroll
    for (int nt = 0; nt < 4; ++nt) {
      const int n = bn + wn * 64 + nt * 16 + lo;
      const float bv = bias[n];
#pragma unroll
      for (int mt = 0; mt < 4; ++mt)
#pragma unroll
        for (int r = 0; r < 4; ++r) {
          const int m = bm + wm * 64 + mt * 16 + g8 * 4 + r;
          Cq[(size_t)m * C3 + n] = f2bf((acc[mt][nt][r] + bv) * sc);
        }
    }
  } else {
#pragma unroll
    for (int nt = 0; nt < 4; ++nt) {
      const int n = bn + wn * 64 + nt * 16 + lo;
      const float bv = bias[n];
      unsigned short* row = vTp + (size_t)(n - 2 * C_DIM) * T_SEQ;
#pragma unroll
      for (int mt = 0; mt < 4; ++mt) {
        const int mbase = (bm + wm * 64 + mt * 16 + g8 * 4) & ~31;
        bf16x4 o4;
#pragma unroll
        for (int r = 0; r < 4; ++r) o4[r] = (short)f2bf(acc[mt][nt][r] + bv);
        *(bf16x4*)(row + mbase + 8 * g8 + 4 * (mt & 1)) = o4;
      }
    }
  }
}

// ---------------------------------------------------------------------------
// gemm2: bf16 MFMA GEMM, B^T input, fp32 out.
// ---------------------------------------------------------------------------
__global__ __launch_bounds__(256) void gemm_bt_mfma(
    const unsigned short* __restrict__ A, const unsigned short* __restrict__ Bt,
    const float* __restrict__ bias, float* __restrict__ C,
    int M, int N, int K) {
  __shared__ unsigned short As[128 * 64];
  __shared__ unsigned short Bs[128 * 64];
  const int tid = threadIdx.x;
  const int wave = tid >> 6, lane = tid & 63;
  const int lo = lane & 15, g8 = lane >> 4;
  const int lo7 = lo & 7;
  const int wm = wave >> 1, wn = wave & 1;
  const int bm = blockIdx.y * 128, bn = blockIdx.x * 128;
  const int drow8 = lane >> 3;
  const int dslot = (lane & 7) * 8;
  const int dsrc = ((lane & 7) ^ drow8) * 8;

  f32x4 acc[4][4];
#pragma unroll
  for (int mt = 0; mt < 4; ++mt)
#pragma unroll
    for (int nt = 0; nt < 4; ++nt) acc[mt][nt] = (f32x4){0.f, 0.f, 0.f, 0.f};

  const unsigned short* Abase = A + (size_t)bm * K;
  const unsigned short* Bbase = Bt + (size_t)bn * K;

  for (int k0 = 0; k0 < K; k0 += 64) {
    __syncthreads();
#pragma unroll
    for (int p = 0; p < 4; ++p) {
      const int r = p * 32 + wave * 8 + drow8;
      gl2lds16(Abase + (size_t)r * K + k0 + dsrc, As + r * 64 + dslot);
      gl2lds16(Bbase + (size_t)r * K + k0 + dsrc, Bs + r * 64 + dslot);
    }
    __syncthreads();

#pragma unroll
    for (int kk = 0; kk < 2; ++kk) {
      bf16x8 a[4], b[4];
#pragma unroll
      for (int mt = 0; mt < 4; ++mt)
        a[mt] = *(const bf16x8*)(
            As + (wm * 64 + mt * 16 + lo) * 64 + (((kk * 4 + g8) ^ lo7) * 8));
#pragma unroll
      for (int nt = 0; nt < 4; ++nt)
        b[nt] = *(const bf16x8*)(
            Bs + (wn * 64 + nt * 16 + lo) * 64 + (((kk * 4 + g8) ^ lo7) * 8));
#pragma unroll
      for (int mt = 0; mt < 4; ++mt)
#pragma unroll
        for (int nt = 0; nt < 4; ++nt)
          acc[mt][nt] = __builtin_amdgcn_mfma_f32_16x16x32_bf16(a[mt], b[nt], acc[mt][nt], 0, 0, 0);
    }
  }

#pragma unroll
  for (int nt = 0; nt < 4; ++nt) {
    const int n = bn + wn * 64 + nt * 16 + lo;
    const float bv = bias[n];
#pragma unroll
    for (int mt = 0; mt < 4; ++mt)
#pragma unroll
      for (int r = 0; r < 4; ++r) {
        const int m = bm + wm * 64 + mt * 16 + g8 * 4 + r;
        C[(size_t)m * N + n] = acc[mt][nt][r] + bv;
      }
  }
}

// ---------------------------------------------------------------------------
// flash v16: QBLK=128 (32 q-rows/wave, 2 q-halves sharing every K/V LDS
// read), KVBLK=64, triple-buffer + counted vmcnt(4) (R16-proven schedule).
// Split-k: q-tile qt (of 32) has 2qt+2 k-tiles; chunks of 22 -> c in 0..2.
// 63 chunks/head, 756 blocks total, depth 2..22. fp32 (O,l) partials to
// slot c; combine sums valid slots.  Chunk c valid iff 11c < qt+1.
// ---------------------------------------------------------------------------
#define PO_SLOT ((size_t)NH * 32 * 128 * 64)  // 3,145,728 floats per slot
#define PL_SLOT ((size_t)NH * 32 * 128)       // 49,152 floats per slot
#define KSTEP   (64 * C3)                     // shorts per k-tile (K stream)

__global__ __launch_bounds__(256) void flash_attn_qb128(
    const unsigned short* __restrict__ qkv,   // [T][2304] bf16 (Qs,K valid)
    const unsigned short* __restrict__ vTp,   // [768][T] bf16, k-permuted
    float* __restrict__ Po, float* __restrict__ Pl) {
  __shared__ unsigned short Ks[3][64 * 64];
  __shared__ unsigned short Vs[3][64 * 64];

  // bijective XCD-contiguous remap (nwg=756: q=94, r=4) -> ~1.5 heads/XCD
  const int orig = blockIdx.x;
  const int xcd = orig & 7;
  const int o8 = orig >> 3;
  const int idx = ((xcd < 4) ? xcd * 95 : 380 + (xcd - 4) * 94) + o8;
  const int h = idx / 63;
  const int rem = idx - h * 63;
  // long-chunks-first enumeration of (qt, c)
  int qt, c;
  if (rem < 30)      { qt = 22 + rem / 3;  c = rem % 3; }
  else if (rem < 52) { int r2 = rem - 30; qt = 11 + (r2 >> 1); c = r2 & 1; }
  else               { qt = rem - 52;      c = 0; }
  const int qt2 = 2 * qt;
  const int k0 = 22 * c;
  const int kmax = qt2 + 2;
  const int k1 = (k0 + 22 < kmax) ? (k0 + 22) : kmax;
  const int T = k1 - k0;                     // 2..22 (always >= 2)

  const int tid = threadIdx.x;
  const int w = tid >> 6;
  const int lane = tid & 63;
  const int lo = lane & 15;
  const int g = lane >> 4;
  const int lo7 = lo & 7;

  const unsigned short* Kg = qkv + C_DIM + h * HD;           // row stride C3
  const unsigned short* Vg = vTp + (size_t)(h * HD) * T_SEQ; // row stride T_SEQ

  const int drow = tid >> 3;                    // 0..31
  const int dslot = (tid & 7) * 8;
  const int dsrc = ((tid & 7) ^ (drow & 7)) * 8;

  // Q B-frags: 2 q-halves x 2 d-halves (Q pre-scaled in gemm1). Issued
  // before the DMAs; in-order vmcnt retirement => vmcnt(4) covers them.
  const int qw0 = w * 32 + lo;                  // local q-row, + qh*16
  bf16x8 qb[2][2];
#pragma unroll
  for (int qh = 0; qh < 2; ++qh)
#pragma unroll
    for (int dh = 0; dh < 2; ++dh)
      qb[qh][dh] = *(const bf16x8*)(
          qkv + (size_t)(qt * 128 + qw0 + qh * 16) * C3 + h * HD + dh * 32 + g * 8);

  // stride-increment DMA pointers (single contiguous k-range)
  const unsigned short* pK0 = Kg + (size_t)k0 * KSTEP + (size_t)drow * C3 + dsrc;
  const unsigned short* pK1 = pK0 + (size_t)32 * C3;
  const unsigned short* pV0 = Vg + (size_t)drow * T_SEQ + k0 * 64 + dsrc;
  const unsigned short* pV1 = pV0 + (size_t)32 * T_SEQ;

  auto stage = [&](int buf) __attribute__((always_inline)) {
    gl2lds16(pK0, Ks[buf] + drow * 64 + dslot);
    gl2lds16(pK1, Ks[buf] + (32 + drow) * 64 + dslot);
    gl2lds16(pV0, Vs[buf] + drow * 64 + dslot);
    gl2lds16(pV1, Vs[buf] + (32 + drow) * 64 + dslot);
    pK0 += KSTEP; pK1 += KSTEP; pV0 += 64; pV1 += 64;
  };

  bf16x8 onesb;
#pragma unroll
  for (int e = 0; e < 8; ++e) onesb[e] = (short)0x3F80;  // bf16 1.0

  // prologue: distance-2 pipeline (T >= 2 always)
  stage(0);
  stage(1);
  asm volatile("s_waitcnt vmcnt(4)" ::: "memory");  // qb + tile0 done
  __builtin_amdgcn_s_barrier();

  f32x4 o_acc[2][4];
  f32x4 lacc[2];
#pragma unroll
  for (int qh = 0; qh < 2; ++qh) {
    lacc[qh] = (f32x4){0.f, 0.f, 0.f, 0.f};
#pragma unroll
    for (int dt = 0; dt < 4; ++dt) o_acc[qh][dt] = (f32x4){0.f, 0.f, 0.f, 0.f};
  }

  int ic = 0, iw = 2;
  int ktc = k0;
  for (int t = 0; t < T; ++t) {
    if (t + 2 < T) stage(iw);
    const unsigned short* Kc = Ks[ic];
    const unsigned short* Vc = Vs[ic];

    // St = K @ Q^T  (scale folded into Q); K-frag shared by both q-halves
    f32x4 st[2][4];
#pragma unroll
    for (int qh = 0; qh < 2; ++qh)
#pragma unroll
      for (int mt = 0; mt < 4; ++mt) st[qh][mt] = (f32x4){0.f, 0.f, 0.f, 0.f};
    __builtin_amdgcn_s_setprio(1);
#pragma unroll
    for (int mt = 0; mt < 4; ++mt)
#pragma unroll
      for (int dh = 0; dh < 2; ++dh) {
        bf16x8 a = *(const bf16x8*)(
            Kc + (mt * 16 + lo) * 64 + (((dh * 4 + g) ^ lo7) * 8));
#pragma unroll
        for (int qh = 0; qh < 2; ++qh)
          st[qh][mt] = __builtin_amdgcn_mfma_f32_16x16x32_bf16(
              a, qb[qh][dh], st[qh][mt], 0, 0, 0);
      }
    __builtin_amdgcn_s_setprio(0);

    // causal mask: only the last chunk's final two k-tiles (kt=2qt, 2qt+1)
    if (ktc >= qt2) {
      const int mb = (ktc == qt2) ? 0 : 64;
#pragma unroll
      for (int qh = 0; qh < 2; ++qh) {
        const int qr = qw0 + qh * 16;
#pragma unroll
        for (int mt = 0; mt < 4; ++mt)
#pragma unroll
          for (int r = 0; r < 4; ++r)
            if (mb + mt * 16 + g * 4 + r > qr) st[qh][mt][r] = -1e30f;
      }
    }

    // no-max softmax: e = exp2(s)  (per-element trunc pack — proven codegen)
    bf16x8 pt[2][2];
#pragma unroll
    for (int qh = 0; qh < 2; ++qh)
#pragma unroll
      for (int kh = 0; kh < 2; ++kh)
#pragma unroll
        for (int jj = 0; jj < 4; ++jj) {
          float e0 = EXP2F(st[qh][kh * 2][jj]);
          float e1 = EXP2F(st[qh][kh * 2 + 1][jj]);
          pt[qh][kh][jj] = (short)f2bf_trunc(e0);
          pt[qh][kh][4 + jj] = (short)f2bf_trunc(e1);
        }

    __builtin_amdgcn_s_setprio(1);
    // l via ones-row MFMA (K-permutation invariant)
#pragma unroll
    for (int qh = 0; qh < 2; ++qh) {
      lacc[qh] = __builtin_amdgcn_mfma_f32_16x16x32_bf16(onesb, pt[qh][0], lacc[qh], 0, 0, 0);
      lacc[qh] = __builtin_amdgcn_mfma_f32_16x16x32_bf16(onesb, pt[qh][1], lacc[qh], 0, 0, 0);
    }
    // O^T += V^T @ P^T ; V-frag shared by both q-halves
#pragma unroll
    for (int dt = 0; dt < 4; ++dt)
#pragma unroll
      for (int kh = 0; kh < 2; ++kh) {
        bf16x8 av = *(const bf16x8*)(
            Vc + (dt * 16 + lo) * 64 + (((kh * 4 + g) ^ lo7) * 8));
#pragma unroll
        for (int qh = 0; qh < 2; ++qh)
          o_acc[qh][dt] = __builtin_amdgcn_mfma_f32_16x16x32_bf16(
              av, pt[qh][kh], o_acc[qh][dt], 0, 0, 0);
      }
    __builtin_amdgcn_s_setprio(0);

    // counted wait: tile t+1 complete; tile t+2's 4 DMAs stay in flight
    if (t + 2 < T)
      asm volatile("s_waitcnt vmcnt(4)" ::: "memory");
    else
      asm volatile("s_waitcnt vmcnt(0)" ::: "memory");
    __builtin_amdgcn_s_barrier();

    ic = (ic == 2) ? 0 : ic + 1;
    iw = (iw == 2) ? 0 : iw + 1;
    ++ktc;
  }

  // flush: unnormalized fp32 partials to slot c
  float* PoS = Po + (((size_t)c * NH + h) * 32 + qt) * (128 * 64);
#pragma unroll
  for (int qh = 0; qh < 2; ++qh)
#pragma unroll
    for (int dt = 0; dt < 4; ++dt)
      *(f32x4*)(PoS + (qw0 + qh * 16) * 64 + dt * 16 + g * 4) = o_acc[qh][dt];
  if (g == 0) {
    float* PlS = Pl + (((size_t)c * NH + h) * 32 + qt) * 128;
#pragma unroll
    for (int qh = 0; qh < 2; ++qh) PlS[qw0 + qh * 16] = lacc[qh][0];
  }
}

// ---------------------------------------------------------------------------
// combine: out = (sum of valid O slots) / (sum of valid l slots) -> bf16
// slot c valid iff 11*c < qt+1  (c=0 always; c=1 qt>=11; c=2 qt>=22)
// ---------------------------------------------------------------------------
__global__ __launch_bounds__(256) void combine_qb128(
    const float* __restrict__ Po, const float* __restrict__ Pl,
    unsigned short* __restrict__ out) {
  const int bid = blockIdx.x;          // 384 = NH*32
  const int h = bid >> 5, qt = bid & 31;
  const int tid = threadIdx.x;
  const int q = tid >> 1;              // 0..127
  const int c0 = (tid & 1) * 32;
  const bool v1 = (qt >= 11);
  const bool v2 = (qt >= 22);
  const size_t base = (size_t)h * 32 + qt;
  const float* P0 = Po + base * (128 * 64) + q * 64 + c0;
  float l = Pl[base * 128 + q];
  if (v1) l += Pl[PL_SLOT + base * 128 + q];
  if (v2) l += Pl[2 * PL_SLOT + base * 128 + q];
  const float inv = 1.0f / l;
  unsigned short ob[32];
#pragma unroll
  for (int e = 0; e < 8; ++e) {
    f32x4 v = *(const f32x4*)(P0 + e * 4);
    if (v1) v += *(const f32x4*)(P0 + PO_SLOT + e * 4);
    if (v2) v += *(const f32x4*)(P0 + 2 * PO_SLOT + e * 4);
#pragma unroll
    for (int r = 0; r < 4; ++r) ob[e * 4 + r] = f2bf(v[r] * inv);
  }
  unsigned short* op = out + (size_t)(qt * 128 + q) * C_DIM + h * 64 + c0;
#pragma unroll
  for (int e2 = 0; e2 < 4; ++e2)
    *(uint4*)(op + e2 * 8) = *(uint4*)(ob + e2 * 8);
}

// ---------------------------------------------------------------------------
extern "C" void kernel_launch(void* const* d_in, const int* in_sizes, int n_in,
                              void* d_out, int out_size, void* d_ws, size_t ws_size,
                              hipStream_t stream) {
  const float* x      = (const float*)d_in[0];
  const float* w_qkv  = (const float*)d_in[1];
  const float* b_qkv  = (const float*)d_in[2];
  const float* w_proj = (const float*)d_in[3];
  const float* b_proj = (const float*)d_in[4];
  float* out = (float*)d_out;

  unsigned short* xb     = (unsigned short*)d_ws;               // [4096,768]
  unsigned short* wqkvT  = xb + (size_t)T_SEQ * C_DIM;          // [2304,768]
  unsigned short* wprojT = wqkvT + (size_t)C3 * C_DIM;          // [768,768]
  unsigned short* qkv    = wprojT + (size_t)C_DIM * C_DIM;      // [4096,2304]
  unsigned short* vTp    = qkv + (size_t)T_SEQ * C3;            // [768,4096]
  unsigned short* attnb  = vTp + (size_t)C_DIM * T_SEQ;         // [4096,768]
  float* Po = (float*)(attnb + (size_t)T_SEQ * C_DIM);          // 3 slots fp32
  float* Pl = Po + 3 * PO_SLOT;                                 // 3 slots fp32

  prep_fused<<<NB_CONV + NB_TQKV + NB_TPROJ, 256, 0, stream>>>(
      x, w_qkv, w_proj, xb, wqkvT, wprojT);

  gemm_qkv<<<dim3(C3 / 128, T_SEQ / 128), 256, 0, stream>>>(
      xb, wqkvT, b_qkv, qkv, vTp, T_SEQ, C3, C_DIM);

  flash_attn_qb128<<<756, 256, 0, stream>>>(qkv, vTp, Po, Pl);

  combine_qb128<<<NH * 32, 256, 0, stream>>>(Po, Pl, attnb);

  gemm_bt_mfma<<<dim3(C_DIM / 128, T_SEQ / 128), 256, 0, stream>>>(
      attnb, wprojT, b_proj, out, T_SEQ, C_DIM, C_DIM);
}

// Round 5
// 187.068 us; speedup vs baseline: 1.0009x; 1.0009x over previous
//
#include <hip/hip_runtime.h>
#include <hip/hip_bf16.h>

// CausalSelfAttention  B=1, T=4096, C=768, H=12, hd=64
// Round 19: R18 post-mortem: flash is per-CU load-imbalance bound
//   (Occupancy 17%; worst CUs carry 66 block-iters while avg is 49.5;
//   CU throughput 1.26 block-iter/us measured). Fix: D=12 chunking ->
//   1224 blocks (depth 2..12) enumerated globally longest-first by
//   blockIdx; capacity 768 (48KB LDS, 3/CU) so 456 blocks BACKFILL as
//   CUs free -> hardware LPT. Body/schedule byte-identical to R18.
//   Compact 6-slot partials (102 recs/head); combine out aliased to xb.

#define T_SEQ 4096
#define C_DIM 768
#define C3    2304
#define NH    12
#define HD    64

typedef __attribute__((ext_vector_type(8))) short bf16x8;
typedef __attribute__((ext_vector_type(4))) short bf16x4;
typedef __attribute__((ext_vector_type(4))) float f32x4;

__device__ inline unsigned short f2bf(float f) {
  union { float f; unsigned u; } v; v.f = f;
  unsigned r = v.u + 0x7fff + ((v.u >> 16) & 1);  // RTNE
  return (unsigned short)(r >> 16);
}
__device__ inline unsigned short f2bf_trunc(float f) {
  union { float f; unsigned u; } v; v.f = f;
  return (unsigned short)(v.u >> 16);  // truncate: fine for P >= 0
}

__device__ inline void gl2lds16(const void* g, void* l) {
  __builtin_amdgcn_global_load_lds(
      (const __attribute__((address_space(1))) unsigned int*)g,
      (__attribute__((address_space(3))) unsigned int*)l, 16, 0, 0);
}

#if __has_builtin(__builtin_amdgcn_exp2f)
#define EXP2F(x) __builtin_amdgcn_exp2f(x)
#else
#define EXP2F(x) exp2f(x)
#endif

// ---------------------------------------------------------------------------
// fused prep: conv x->bf16 | transpose w_qkv | transpose w_proj
// ---------------------------------------------------------------------------
#define NB_CONV  (T_SEQ * C_DIM / 2048)          // 1536
#define NB_TQKV  ((C3 / 32) * (C_DIM / 32))      // 1728
#define NB_TPROJ ((C_DIM / 32) * (C_DIM / 32))   // 576

__global__ __launch_bounds__(256) void prep_fused(
    const float* __restrict__ x, const float* __restrict__ w_qkv,
    const float* __restrict__ w_proj, unsigned short* __restrict__ xb,
    unsigned short* __restrict__ wqkvT, unsigned short* __restrict__ wprojT) {
  __shared__ float t[32][33];
  const int b = blockIdx.x;
  const int tid = threadIdx.x;

  if (b < NB_CONV) {
    int i = (b * 256 + tid) * 8;
    float4 v0 = *(const float4*)(x + i);
    float4 v1 = *(const float4*)(x + i + 4);
    unsigned short o[8] = {f2bf(v0.x), f2bf(v0.y), f2bf(v0.z), f2bf(v0.w),
                           f2bf(v1.x), f2bf(v1.y), f2bf(v1.z), f2bf(v1.w)};
    *(uint4*)(xb + i) = *(uint4*)o;
    return;
  }
  const float* in;
  unsigned short* outT;
  int R, Cc, bi;
  if (b < NB_CONV + NB_TQKV) {
    in = w_qkv; outT = wqkvT; R = C_DIM; Cc = C3; bi = b - NB_CONV;
  } else {
    in = w_proj; outT = wprojT; R = C_DIM; Cc = C_DIM; bi = b - NB_CONV - NB_TQKV;
  }
  const int tx = tid & 31, ty = tid >> 5;
  const int c0 = (bi % (Cc / 32)) * 32, r0 = (bi / (Cc / 32)) * 32;
#pragma unroll
  for (int i = 0; i < 4; ++i) {
    int r = ty + i * 8;
    t[r][tx] = in[(size_t)(r0 + r) * Cc + c0 + tx];
  }
  __syncthreads();
#pragma unroll
  for (int i = 0; i < 4; ++i) {
    int c = ty + i * 8;
    outT[(size_t)(c0 + c) * R + r0 + tx] = f2bf(t[tx][c]);
  }
}

// ---------------------------------------------------------------------------
// gemm1: qkv = xb @ wqkvT^T + b_qkv; V blocks write k-permuted vTp directly.
// Q columns (n < 768) pre-scaled by 0.125*log2(e).
// ---------------------------------------------------------------------------
__global__ __launch_bounds__(256) void gemm_qkv(
    const unsigned short* __restrict__ A, const unsigned short* __restrict__ Bt,
    const float* __restrict__ bias, unsigned short* __restrict__ Cq,
    unsigned short* __restrict__ vTp, int M, int N, int K) {
  __shared__ unsigned short As[128 * 64];
  __shared__ unsigned short Bs[128 * 64];
  const int tid = threadIdx.x;
  const int wave = tid >> 6, lane = tid & 63;
  const int lo = lane & 15, g8 = lane >> 4;
  const int lo7 = lo & 7;
  const int wm = wave >> 1, wn = wave & 1;
  const int bm = blockIdx.y * 128, bn = blockIdx.x * 128;
  const int drow8 = lane >> 3;               // 0..7
  const int dslot = (lane & 7) * 8;
  const int dsrc = ((lane & 7) ^ drow8) * 8; // swizzled source chunk

  f32x4 acc[4][4];
#pragma unroll
  for (int mt = 0; mt < 4; ++mt)
#pragma unroll
    for (int nt = 0; nt < 4; ++nt) acc[mt][nt] = (f32x4){0.f, 0.f, 0.f, 0.f};

  const unsigned short* Abase = A + (size_t)bm * K;
  const unsigned short* Bbase = Bt + (size_t)bn * K;

  for (int k0 = 0; k0 < K; k0 += 64) {
    __syncthreads();
#pragma unroll
    for (int p = 0; p < 4; ++p) {
      const int r = p * 32 + wave * 8 + drow8;
      gl2lds16(Abase + (size_t)r * K + k0 + dsrc, As + r * 64 + dslot);
      gl2lds16(Bbase + (size_t)r * K + k0 + dsrc, Bs + r * 64 + dslot);
    }
    __syncthreads();

#pragma unroll
    for (int kk = 0; kk < 2; ++kk) {
      bf16x8 a[4], b[4];
#pragma unroll
      for (int mt = 0; mt < 4; ++mt)
        a[mt] = *(const bf16x8*)(
            As + (wm * 64 + mt * 16 + lo) * 64 + (((kk * 4 + g8) ^ lo7) * 8));
#pragma unroll
      for (int nt = 0; nt < 4; ++nt)
        b[nt] = *(const bf16x8*)(
            Bs + (wn * 64 + nt * 16 + lo) * 64 + (((kk * 4 + g8) ^ lo7) * 8));
#pragma unroll
      for (int mt = 0; mt < 4; ++mt)
#pragma unroll
        for (int nt = 0; nt < 4; ++nt)
          acc[mt][nt] = __builtin_amdgcn_mfma_f32_16x16x32_bf16(a[mt], b[nt], acc[mt][nt], 0, 0, 0);
    }
  }

  if (bn < 2 * C_DIM) {
    const float sc = (bn < C_DIM) ? 0.18033688011112042f : 1.0f;  // 0.125*log2e
#pragma unroll
    for (int nt = 0; nt < 4; ++nt) {
      const int n = bn + wn * 64 + nt * 16 + lo;
      const float bv = bias[n];
#pragma unroll
      for (int mt = 0; mt < 4; ++mt)
#pragma unroll
        for (int r = 0; r < 4; ++r) {
          const int m = bm + wm * 64 + mt * 16 + g8 * 4 + r;
          Cq[(size_t)m * C3 + n] = f2bf((acc[mt][nt][r] + bv) * sc);
        }
    }
  } else {
#pragma unroll
    for (int nt = 0; nt < 4; ++nt) {
      const int n = bn + wn * 64 + nt * 16 + lo;
      const float bv = bias[n];
      unsigned short* row = vTp + (size_t)(n - 2 * C_DIM) * T_SEQ;
#pragma unroll
      for (int mt = 0; mt < 4; ++mt) {
        const int mbase = (bm + wm * 64 + mt * 16 + g8 * 4) & ~31;
        bf16x4 o4;
#pragma unroll
        for (int r = 0; r < 4; ++r) o4[r] = (short)f2bf(acc[mt][nt][r] + bv);
        *(bf16x4*)(row + mbase + 8 * g8 + 4 * (mt & 1)) = o4;
      }
    }
  }
}

// ---------------------------------------------------------------------------
// gemm2: bf16 MFMA GEMM, B^T input, fp32 out.
// ---------------------------------------------------------------------------
__global__ __launch_bounds__(256) void gemm_bt_mfma(
    const unsigned short* __restrict__ A, const unsigned short* __restrict__ Bt,
    const float* __restrict__ bias, float* __restrict__ C,
    int M, int N, int K) {
  __shared__ unsigned short As[128 * 64];
  __shared__ unsigned short Bs[128 * 64];
  const int tid = threadIdx.x;
  const int wave = tid >> 6, lane = tid & 63;
  const int lo = lane & 15, g8 = lane >> 4;
  const int lo7 = lo & 7;
  const int wm = wave >> 1, wn = wave & 1;
  const int bm = blockIdx.y * 128, bn = blockIdx.x * 128;
  const int drow8 = lane >> 3;
  const int dslot = (lane & 7) * 8;
  const int dsrc = ((lane & 7) ^ drow8) * 8;

  f32x4 acc[4][4];
#pragma unroll
  for (int mt = 0; mt < 4; ++mt)
#pragma unroll
    for (int nt = 0; nt < 4; ++nt) acc[mt][nt] = (f32x4){0.f, 0.f, 0.f, 0.f};

  const unsigned short* Abase = A + (size_t)bm * K;
  const unsigned short* Bbase = Bt + (size_t)bn * K;

  for (int k0 = 0; k0 < K; k0 += 64) {
    __syncthreads();
#pragma unroll
    for (int p = 0; p < 4; ++p) {
      const int r = p * 32 + wave * 8 + drow8;
      gl2lds16(Abase + (size_t)r * K + k0 + dsrc, As + r * 64 + dslot);
      gl2lds16(Bbase + (size_t)r * K + k0 + dsrc, Bs + r * 64 + dslot);
    }
    __syncthreads();

#pragma unroll
    for (int kk = 0; kk < 2; ++kk) {
      bf16x8 a[4], b[4];
#pragma unroll
      for (int mt = 0; mt < 4; ++mt)
        a[mt] = *(const bf16x8*)(
            As + (wm * 64 + mt * 16 + lo) * 64 + (((kk * 4 + g8) ^ lo7) * 8));
#pragma unroll
      for (int nt = 0; nt < 4; ++nt)
        b[nt] = *(const bf16x8*)(
            Bs + (wn * 64 + nt * 16 + lo) * 64 + (((kk * 4 + g8) ^ lo7) * 8));
#pragma unroll
      for (int mt = 0; mt < 4; ++mt)
#pragma unroll
        for (int nt = 0; nt < 4; ++nt)
          acc[mt][nt] = __builtin_amdgcn_mfma_f32_16x16x32_bf16(a[mt], b[nt], acc[mt][nt], 0, 0, 0);
    }
  }

#pragma unroll
  for (int nt = 0; nt < 4; ++nt) {
    const int n = bn + wn * 64 + nt * 16 + lo;
    const float bv = bias[n];
#pragma unroll
    for (int mt = 0; mt < 4; ++mt)
#pragma unroll
      for (int r = 0; r < 4; ++r) {
        const int m = bm + wm * 64 + mt * 16 + g8 * 4 + r;
        C[(size_t)m * N + n] = acc[mt][nt][r] + bv;
      }
  }
}

// ---------------------------------------------------------------------------
// flash v17: QBLK=128, KVBLK=64, D=12 chunking, hardware-LPT dispatch.
// Per (h, qt of 32): n = 2qt+2 k-tiles split into chunks of 12 (last chunk
// = tail 2..10). 1224 blocks total, enumerated longest-first:
//   u <  900 : full chunks (depth 12), 75/head
//   u >= 900 : tails descending by size (10,8,6,4,2)
// Capacity 768 (48KB LDS) -> 456 queued blocks backfill freed CUs.
// Compact partial records: slot c of qt valid iff qt >= 6c;
//   rec = c*(35-3c) + (qt - 6c), 102 recs/head.
// Body/schedule identical to R18 (triple-buffer, counted vmcnt(4)).
// ---------------------------------------------------------------------------
#define NREC   102
#define PO_REC (128 * 64)
#define KSTEP  (64 * C3)                   // shorts per k-tile (K stream)

__global__ __launch_bounds__(256) void flash_attn_d12(
    const unsigned short* __restrict__ qkv,   // [T][2304] bf16 (Qs,K valid)
    const unsigned short* __restrict__ vTp,   // [768][T] bf16, k-permuted
    float* __restrict__ Po, float* __restrict__ Pl) {
  __shared__ unsigned short Ks[3][64 * 64];
  __shared__ unsigned short Vs[3][64 * 64];

  // longest-first decode of blockIdx.x -> (h, qt, c)
  const int u = blockIdx.x;
  int h, qt, c;
  if (u < 900) {                       // full chunks, depth 12
    h = u / 75;
    const int w = u % 75;
    if (w < 15)      { qt = 29 + w / 5;          c = w % 5; }
    else if (w < 39) { const int r = w - 15; qt = 23 + r / 4; c = r % 4; }
    else if (w < 57) { const int r = w - 39; qt = 17 + r / 3; c = r % 3; }
    else if (w < 69) { const int r = w - 57; qt = 11 + r / 2; c = r % 2; }
    else             { qt = 5 + (w - 69);        c = 0; }
  } else {                             // tails, sizes 10,8,6,4,2
    const int v = u - 900;
    int m, r;
    if (v < 60)       { m = 5; r = v; }
    else if (v < 120) { m = 4; r = v - 60; }
    else if (v < 180) { m = 3; r = v - 120; }
    else if (v < 252) { m = 2; r = v - 180; }
    else              { m = 1; r = v - 252; }
    const int per = (m >= 3) ? 5 : 6;
    h = r / per;
    qt = (m - 1) + 6 * (r % per);
    c = (qt + 1) / 6;
  }
  const int n = 2 * qt + 2;
  const int k0 = 12 * c;
  const int T = (n - k0 < 12) ? (n - k0) : 12;   // 2..12
  const int qt2 = 2 * qt;
  const int rec = c * (35 - 3 * c) + (qt - 6 * c);

  const int tid = threadIdx.x;
  const int w = tid >> 6;
  const int lane = tid & 63;
  const int lo = lane & 15;
  const int g = lane >> 4;
  const int lo7 = lo & 7;

  const unsigned short* Kg = qkv + C_DIM + h * HD;           // row stride C3
  const unsigned short* Vg = vTp + (size_t)(h * HD) * T_SEQ; // row stride T_SEQ

  const int drow = tid >> 3;                    // 0..31
  const int dslot = (tid & 7) * 8;
  const int dsrc = ((tid & 7) ^ (drow & 7)) * 8;

  // Q B-frags: 2 q-halves x 2 d-halves (Q pre-scaled in gemm1). Issued
  // before the DMAs; in-order vmcnt retirement => vmcnt(4) covers them.
  const int qw0 = w * 32 + lo;                  // local q-row, + qh*16
  bf16x8 qb[2][2];
#pragma unroll
  for (int qh = 0; qh < 2; ++qh)
#pragma unroll
    for (int dh = 0; dh < 2; ++dh)
      qb[qh][dh] = *(const bf16x8*)(
          qkv + (size_t)(qt * 128 + qw0 + qh * 16) * C3 + h * HD + dh * 32 + g * 8);

  // stride-increment DMA pointers (single contiguous k-range)
  const unsigned short* pK0 = Kg + (size_t)k0 * KSTEP + (size_t)drow * C3 + dsrc;
  const unsigned short* pK1 = pK0 + (size_t)32 * C3;
  const unsigned short* pV0 = Vg + (size_t)drow * T_SEQ + k0 * 64 + dsrc;
  const unsigned short* pV1 = pV0 + (size_t)32 * T_SEQ;

  auto stage = [&](int buf) __attribute__((always_inline)) {
    gl2lds16(pK0, Ks[buf] + drow * 64 + dslot);
    gl2lds16(pK1, Ks[buf] + (32 + drow) * 64 + dslot);
    gl2lds16(pV0, Vs[buf] + drow * 64 + dslot);
    gl2lds16(pV1, Vs[buf] + (32 + drow) * 64 + dslot);
    pK0 += KSTEP; pK1 += KSTEP; pV0 += 64; pV1 += 64;
  };

  bf16x8 onesb;
#pragma unroll
  for (int e = 0; e < 8; ++e) onesb[e] = (short)0x3F80;  // bf16 1.0

  // prologue: distance-2 pipeline (T >= 2 always)
  stage(0);
  stage(1);
  asm volatile("s_waitcnt vmcnt(4)" ::: "memory");  // qb + tile0 done
  __builtin_amdgcn_s_barrier();

  f32x4 o_acc[2][4];
  f32x4 lacc[2];
#pragma unroll
  for (int qh = 0; qh < 2; ++qh) {
    lacc[qh] = (f32x4){0.f, 0.f, 0.f, 0.f};
#pragma unroll
    for (int dt = 0; dt < 4; ++dt) o_acc[qh][dt] = (f32x4){0.f, 0.f, 0.f, 0.f};
  }

  int ic = 0, iw = 2;
  int ktc = k0;
  for (int t = 0; t < T; ++t) {
    if (t + 2 < T) stage(iw);
    const unsigned short* Kc = Ks[ic];
    const unsigned short* Vc = Vs[ic];

    // St = K @ Q^T  (scale folded into Q); K-frag shared by both q-halves
    f32x4 st[2][4];
#pragma unroll
    for (int qh = 0; qh < 2; ++qh)
#pragma unroll
      for (int mt = 0; mt < 4; ++mt) st[qh][mt] = (f32x4){0.f, 0.f, 0.f, 0.f};
    __builtin_amdgcn_s_setprio(1);
#pragma unroll
    for (int mt = 0; mt < 4; ++mt)
#pragma unroll
      for (int dh = 0; dh < 2; ++dh) {
        bf16x8 a = *(const bf16x8*)(
            Kc + (mt * 16 + lo) * 64 + (((dh * 4 + g) ^ lo7) * 8));
#pragma unroll
        for (int qh = 0; qh < 2; ++qh)
          st[qh][mt] = __builtin_amdgcn_mfma_f32_16x16x32_bf16(
              a, qb[qh][dh], st[qh][mt], 0, 0, 0);
      }
    __builtin_amdgcn_s_setprio(0);

    // causal mask: only the final two k-tiles (kt = 2qt, 2qt+1)
    if (ktc >= qt2) {
      const int mb = (ktc == qt2) ? 0 : 64;
#pragma unroll
      for (int qh = 0; qh < 2; ++qh) {
        const int qr = qw0 + qh * 16;
#pragma unroll
        for (int mt = 0; mt < 4; ++mt)
#pragma unroll
          for (int r = 0; r < 4; ++r)
            if (mb + mt * 16 + g * 4 + r > qr) st[qh][mt][r] = -1e30f;
      }
    }

    // no-max softmax: e = exp2(s)  (per-element trunc pack — proven codegen)
    bf16x8 pt[2][2];
#pragma unroll
    for (int qh = 0; qh < 2; ++qh)
#pragma unroll
      for (int kh = 0; kh < 2; ++kh)
#pragma unroll
        for (int jj = 0; jj < 4; ++jj) {
          float e0 = EXP2F(st[qh][kh * 2][jj]);
          float e1 = EXP2F(st[qh][kh * 2 + 1][jj]);
          pt[qh][kh][jj] = (short)f2bf_trunc(e0);
          pt[qh][kh][4 + jj] = (short)f2bf_trunc(e1);
        }

    __builtin_amdgcn_s_setprio(1);
    // l via ones-row MFMA (K-permutation invariant)
#pragma unroll
    for (int qh = 0; qh < 2; ++qh) {
      lacc[qh] = __builtin_amdgcn_mfma_f32_16x16x32_bf16(onesb, pt[qh][0], lacc[qh], 0, 0, 0);
      lacc[qh] = __builtin_amdgcn_mfma_f32_16x16x32_bf16(onesb, pt[qh][1], lacc[qh], 0, 0, 0);
    }
    // O^T += V^T @ P^T ; V-frag shared by both q-halves
#pragma unroll
    for (int dt = 0; dt < 4; ++dt)
#pragma unroll
      for (int kh = 0; kh < 2; ++kh) {
        bf16x8 av = *(const bf16x8*)(
            Vc + (dt * 16 + lo) * 64 + (((kh * 4 + g) ^ lo7) * 8));
#pragma unroll
        for (int qh = 0; qh < 2; ++qh)
          o_acc[qh][dt] = __builtin_amdgcn_mfma_f32_16x16x32_bf16(
              av, pt[qh][kh], o_acc[qh][dt], 0, 0, 0);
      }
    __builtin_amdgcn_s_setprio(0);

    // counted wait: tile t+1 complete; tile t+2's 4 DMAs stay in flight
    if (t + 2 < T)
      asm volatile("s_waitcnt vmcnt(4)" ::: "memory");
    else
      asm volatile("s_waitcnt vmcnt(0)" ::: "memory");
    __builtin_amdgcn_s_barrier();

    ic = (ic == 2) ? 0 : ic + 1;
    iw = (iw == 2) ? 0 : iw + 1;
    ++ktc;
  }

  // flush: unnormalized fp32 partials to compact record
  float* PoS = Po + ((size_t)h * NREC + rec) * PO_REC;
#pragma unroll
  for (int qh = 0; qh < 2; ++qh)
#pragma unroll
    for (int dt = 0; dt < 4; ++dt)
      *(f32x4*)(PoS + (qw0 + qh * 16) * 64 + dt * 16 + g * 4) = o_acc[qh][dt];
  if (g == 0) {
    float* PlS = Pl + ((size_t)h * NREC + rec) * 128;
#pragma unroll
    for (int qh = 0; qh < 2; ++qh) PlS[qw0 + qh * 16] = lacc[qh][0];
  }
}

// ---------------------------------------------------------------------------
// combine: out = (sum of valid recs) / (sum of valid l) -> bf16 [4096][768]
// slot c valid iff qt >= 6c; cmax = qt/6 (0..5)
// ---------------------------------------------------------------------------
__global__ __launch_bounds__(256) void combine_d12(
    const float* __restrict__ Po, const float* __restrict__ Pl,
    unsigned short* __restrict__ out) {
  const int bid = blockIdx.x;          // 384 = NH*32
  const int h = bid >> 5, qt = bid & 31;
  const int tid = threadIdx.x;
  const int q = tid >> 1;              // 0..127
  const int c0 = (tid & 1) * 32;
  const int cmax = qt / 6;
  float l = 0.f;
  f32x4 acc[8];
#pragma unroll
  for (int e = 0; e < 8; ++e) acc[e] = (f32x4){0.f, 0.f, 0.f, 0.f};
  for (int c = 0; c <= cmax; ++c) {
    const int rec = c * (35 - 3 * c) + (qt - 6 * c);
    const size_t base = (size_t)h * NREC + rec;
    l += Pl[base * 128 + q];
    const float* P = Po + base * PO_REC + q * 64 + c0;
#pragma unroll
    for (int e = 0; e < 8; ++e) acc[e] += *(const f32x4*)(P + e * 4);
  }
  const float inv = 1.0f / l;
  unsigned short ob[32];
#pragma unroll
  for (int e = 0; e < 8; ++e)
#pragma unroll
    for (int r = 0; r < 4; ++r) ob[e * 4 + r] = f2bf(acc[e][r] * inv);
  unsigned short* op = out + (size_t)(qt * 128 + q) * C_DIM + h * 64 + c0;
#pragma unroll
  for (int e2 = 0; e2 < 4; ++e2)
    *(uint4*)(op + e2 * 8) = *(uint4*)(ob + e2 * 8);
}

// ---------------------------------------------------------------------------
extern "C" void kernel_launch(void* const* d_in, const int* in_sizes, int n_in,
                              void* d_out, int out_size, void* d_ws, size_t ws_size,
                              hipStream_t stream) {
  const float* x      = (const float*)d_in[0];
  const float* w_qkv  = (const float*)d_in[1];
  const float* b_qkv  = (const float*)d_in[2];
  const float* w_proj = (const float*)d_in[3];
  const float* b_proj = (const float*)d_in[4];
  float* out = (float*)d_out;

  unsigned short* xb     = (unsigned short*)d_ws;               // [4096,768]
  unsigned short* wqkvT  = xb + (size_t)T_SEQ * C_DIM;          // [2304,768]
  unsigned short* wprojT = wqkvT + (size_t)C3 * C_DIM;          // [768,768]
  unsigned short* qkv    = wprojT + (size_t)C_DIM * C_DIM;      // [4096,2304]
  unsigned short* vTp    = qkv + (size_t)T_SEQ * C3;            // [768,4096]
  unsigned short* attnb  = xb;  // alias: xb is dead after gemm_qkv
  float* Po = (float*)(vTp + (size_t)C_DIM * T_SEQ);            // compact recs
  float* Pl = Po + (size_t)NH * NREC * PO_REC;

  prep_fused<<<NB_CONV + NB_TQKV + NB_TPROJ, 256, 0, stream>>>(
      x, w_qkv, w_proj, xb, wqkvT, wprojT);

  gemm_qkv<<<dim3(C3 / 128, T_SEQ / 128), 256, 0, stream>>>(
      xb, wqkvT, b_qkv, qkv, vTp, T_SEQ, C3, C_DIM);

  flash_attn_d12<<<1224, 256, 0, stream>>>(qkv, vTp, Po, Pl);

  combine_d12<<<NH * 32, 256, 0, stream>>>(Po, Pl, attnb);

  gemm_bt_mfma<<<dim3(C_DIM / 128, T_SEQ / 128), 256, 0, stream>>>(
      attnb, wprojT, b_proj, out, T_SEQ, C_DIM, C_DIM);
}